// Round 1
// baseline (269.061 us; speedup 1.0000x reference)
//
#include <hip/hip_runtime.h>

#define EMBED 1024
#define HEADS 8
#define DIM_HEAD 64
#define INNER 512
#define BATCH 16
#define SEQ 2048
// scale = DIM_HEAD^-0.5 = 0.125

// ---------------------------------------------------------------------------
// k0: q[h,d] = token . Wq[h*64+d]; qk[h][e] = 0.125 * sum_d q[h,d]*Wkv[h*64+d][e]
// grid: 8 (one per head), block 256
__global__ void ap_k0_qk(const float* __restrict__ token, const float* __restrict__ Wq,
                         const float* __restrict__ Wkv, float* __restrict__ qk) {
    __shared__ float q_s[DIM_HEAD];
    const int h = blockIdx.x;
    const int t = threadIdx.x;
    const int d = t >> 2, qq = t & 3;
    const float4* tok4 = (const float4*)token;
    const float4* Wq4  = (const float4*)Wq;
    const float4* Wkv4 = (const float4*)Wkv;

    // step 1: q[d], 4 threads per d
    float acc = 0.f;
    const int rowbase = (h * DIM_HEAD + d) * (EMBED / 4);
    for (int j = 0; j < 64; ++j) {
        int idx = qq + 4 * j;
        float4 a = tok4[idx];
        float4 b = Wq4[rowbase + idx];
        acc += a.x * b.x + a.y * b.y + a.z * b.z + a.w * b.w;
    }
    acc += __shfl_xor(acc, 1);
    acc += __shfl_xor(acc, 2);
    if (qq == 0) q_s[d] = acc;
    __syncthreads();

    // step 2: qk[h][e4=t]
    float4 a4 = make_float4(0.f, 0.f, 0.f, 0.f);
    for (int dd = 0; dd < DIM_HEAD; ++dd) {
        float qv = q_s[dd];
        float4 w = Wkv4[(h * DIM_HEAD + dd) * (EMBED / 4) + t];
        a4.x += qv * w.x; a4.y += qv * w.y; a4.z += qv * w.z; a4.w += qv * w.w;
    }
    a4.x *= 0.125f; a4.y *= 0.125f; a4.z *= 0.125f; a4.w *= 0.125f;
    ((float4*)qk)[h * (EMBED / 4) + t] = a4;
}

// ---------------------------------------------------------------------------
// k1: sim[b][h][s] = qk[h] . x[b,s]
// grid: 32768/8 = 4096 blocks, block 256 = 4 waves, each wave does 2 rows
__global__ __launch_bounds__(256) void ap_k1_sim(const float* __restrict__ x,
                                                 const float* __restrict__ qk,
                                                 float* __restrict__ sim) {
    __shared__ float4 qk_s[HEADS * EMBED / 4];  // 2048 float4 = 32 KB
    const int t = threadIdx.x;
    const float4* qk4 = (const float4*)qk;
#pragma unroll
    for (int j = 0; j < 8; ++j) qk_s[t + 256 * j] = qk4[t + 256 * j];
    __syncthreads();

    const int w = t >> 6, lane = t & 63;
    const long r0 = (long)blockIdx.x * 8 + w * 2;   // 2048%8==0 -> never straddles b
    const int b = (int)(r0 >> 11), s = (int)(r0 & 2047);
    const float4* xr0 = (const float4*)x + r0 * (EMBED / 4);
    const float4* xr1 = xr0 + (EMBED / 4);

    float acc0[8], acc1[8];
#pragma unroll
    for (int h = 0; h < 8; ++h) { acc0[h] = 0.f; acc1[h] = 0.f; }

#pragma unroll
    for (int k = 0; k < 4; ++k) {
        const int e4 = k * 64 + lane;
        float4 a = xr0[e4];
        float4 c = xr1[e4];
#pragma unroll
        for (int h = 0; h < 8; ++h) {
            float4 qv = qk_s[h * 256 + e4];
            acc0[h] += a.x * qv.x + a.y * qv.y + a.z * qv.z + a.w * qv.w;
            acc1[h] += c.x * qv.x + c.y * qv.y + c.z * qv.z + c.w * qv.w;
        }
    }
#pragma unroll
    for (int h = 0; h < 8; ++h) {
#pragma unroll
        for (int off = 32; off; off >>= 1) {
            acc0[h] += __shfl_xor(acc0[h], off);
            acc1[h] += __shfl_xor(acc1[h], off);
        }
    }
    if (lane == 0) {
#pragma unroll
        for (int h = 0; h < 8; ++h) {
            sim[((long)(b * 8 + h) * SEQ) + s]     = acc0[h];
            sim[((long)(b * 8 + h) * SEQ) + s + 1] = acc1[h];
        }
    }
}

// ---------------------------------------------------------------------------
// k2: softmax in place over s for each (b,h) row. grid 128, block 256
__global__ void ap_k2_softmax(float* __restrict__ sim) {
    __shared__ float red[8];
    const int t = threadIdx.x;
    float* row = sim + (long)blockIdx.x * SEQ;
    float v[8];
    float m = -1e30f;
#pragma unroll
    for (int j = 0; j < 8; ++j) { v[j] = row[t + 256 * j]; m = fmaxf(m, v[j]); }
#pragma unroll
    for (int off = 32; off; off >>= 1) m = fmaxf(m, __shfl_xor(m, off));
    const int w = t >> 6, lane = t & 63;
    if (lane == 0) red[w] = m;
    __syncthreads();
    m = fmaxf(fmaxf(red[0], red[1]), fmaxf(red[2], red[3]));
    float ssum = 0.f;
#pragma unroll
    for (int j = 0; j < 8; ++j) { v[j] = __expf(v[j] - m); ssum += v[j]; }
#pragma unroll
    for (int off = 32; off; off >>= 1) ssum += __shfl_xor(ssum, off);
    if (lane == 0) red[4 + w] = ssum;
    __syncthreads();
    const float inv = 1.f / (red[4] + red[5] + red[6] + red[7]);
#pragma unroll
    for (int j = 0; j < 8; ++j) row[t + 256 * j] = v[j] * inv;
}

// ---------------------------------------------------------------------------
// k3: xpart[b][chunk][h][e] = sum_{s in chunk} attn[b,h,s] * x[b,s,e]
// grid (16 chunks, 16 b), block 256; thread owns float4 of e; acc[8] in regs
__global__ __launch_bounds__(256) void ap_k3_wsum(const float* __restrict__ x,
                                                  const float* __restrict__ attn,
                                                  float* __restrict__ xpart) {
    __shared__ float at_s[HEADS * 128];   // 4 KB
    const int chunk = blockIdx.x, b = blockIdx.y;
    const int t = threadIdx.x;
    const int s0 = chunk * 128;
#pragma unroll
    for (int j = 0; j < 4; ++j) {
        int i = t + 256 * j;
        int h = i >> 7, sl = i & 127;
        at_s[i] = attn[((long)(b * 8 + h) * SEQ) + s0 + sl];
    }
    __syncthreads();

    float4 acc[8];
#pragma unroll
    for (int h = 0; h < 8; ++h) acc[h] = make_float4(0.f, 0.f, 0.f, 0.f);

    const float4* x4 = (const float4*)x + (long)(b * SEQ + s0) * (EMBED / 4);
    for (int sl = 0; sl < 128; ++sl) {
        float4 xv = x4[(long)sl * 256 + t];
#pragma unroll
        for (int h = 0; h < 8; ++h) {
            float a = at_s[h * 128 + sl];
            acc[h].x += a * xv.x; acc[h].y += a * xv.y;
            acc[h].z += a * xv.z; acc[h].w += a * xv.w;
        }
    }
    float4* xp4 = (float4*)xpart;
#pragma unroll
    for (int h = 0; h < 8; ++h)
        xp4[(((long)(b * 16 + chunk) * 8 + h) * 256) + t] = acc[h];
}

// k3b: xbar[b][h][e] = sum_chunk xpart. grid 128, block 256
__global__ void ap_k3b_combine(const float* __restrict__ xpart, float* __restrict__ xbar) {
    const int b = blockIdx.x >> 3, h = blockIdx.x & 7;
    const int t = threadIdx.x;
    const float4* xp4 = (const float4*)xpart;
    float4 sum = make_float4(0.f, 0.f, 0.f, 0.f);
#pragma unroll
    for (int c = 0; c < 16; ++c) {
        float4 v = xp4[(((long)(b * 16 + c) * 8 + h) * 256) + t];
        sum.x += v.x; sum.y += v.y; sum.z += v.z; sum.w += v.w;
    }
    ((float4*)xbar)[(long)(b * 8 + h) * 256 + t] = sum;
}

// ---------------------------------------------------------------------------
// k4: om[b][h*64+d] = Wv_row(h,d) . xbar[b][h]   (Wv = rows INNER.. of Wkv)
// grid 128 (b,h), block 256: 4 threads per d
__global__ void ap_k4_vproj(const float* __restrict__ Wkv, const float* __restrict__ xbar,
                            float* __restrict__ om) {
    __shared__ float4 xb_s[256];
    const int b = blockIdx.x >> 3, h = blockIdx.x & 7;
    const int t = threadIdx.x;
    xb_s[t] = ((const float4*)xbar)[(long)(b * 8 + h) * 256 + t];
    __syncthreads();
    const int d = t >> 2, qq = t & 3;
    const float4* W4 = (const float4*)Wkv + (long)(INNER + h * DIM_HEAD + d) * (EMBED / 4);
    float acc = 0.f;
    for (int j = 0; j < 64; ++j) {
        int idx = qq + 4 * j;
        float4 w = W4[idx];
        float4 xv = xb_s[idx];
        acc += w.x * xv.x + w.y * xv.y + w.z * xv.z + w.w * xv.w;
    }
    acc += __shfl_xor(acc, 1);
    acc += __shfl_xor(acc, 2);
    if (qq == 0) om[b * INNER + h * DIM_HEAD + d] = acc;
}

// ---------------------------------------------------------------------------
// k5: out[b][e] = bo[e] + om[b] . Wo[e]   grid (16 chunks of 64 e, 16 b), block 256
__global__ void ap_k5_final(const float* __restrict__ Wo, const float* __restrict__ bo,
                            const float* __restrict__ om, float* __restrict__ out) {
    __shared__ float4 om_s[INNER / 4];  // 2 KB
    const int chunk = blockIdx.x, b = blockIdx.y;
    const int t = threadIdx.x;
    if (t < 128) om_s[t] = ((const float4*)om)[b * (INNER / 4) + t];
    __syncthreads();
    const int eo = t >> 2, qq = t & 3;
    const int e = chunk * 64 + eo;
    const float4* W4 = (const float4*)Wo + (long)e * (INNER / 4);
    float acc = 0.f;
    for (int j = 0; j < 32; ++j) {
        int idx = qq + 4 * j;
        float4 w = W4[idx];
        float4 v = om_s[idx];
        acc += w.x * v.x + w.y * v.y + w.z * v.z + w.w * v.w;
    }
    acc += __shfl_xor(acc, 1);
    acc += __shfl_xor(acc, 2);
    if (qq == 0) out[b * EMBED + e] = acc + bo[e];
}

// ---------------------------------------------------------------------------
extern "C" void kernel_launch(void* const* d_in, const int* in_sizes, int n_in,
                              void* d_out, int out_size, void* d_ws, size_t ws_size,
                              hipStream_t stream) {
    const float* x     = (const float*)d_in[0];  // 16*2048*1024
    const float* token = (const float*)d_in[1];  // 1024
    const float* Wq    = (const float*)d_in[2];  // 512*1024
    const float* Wkv   = (const float*)d_in[3];  // 1024*1024
    const float* Wo    = (const float*)d_in[4];  // 1024*512
    const float* bo    = (const float*)d_in[5];  // 1024
    float* out = (float*)d_out;                  // 16*1024
    float* ws = (float*)d_ws;

    float* qk    = ws;            // 8*1024            = 8192 floats
    float* sim   = ws + 8192;     // 16*8*2048         = 262144
    float* xpart = ws + 270336;   // 16*16*8*1024      = 2097152
    float* xbar  = ws + 2367488;  // 16*8*1024         = 131072
    float* om    = ws + 2498560;  // 16*512            = 8192
    // total ~2.51M floats ≈ 10 MB of d_ws

    ap_k0_qk<<<8, 256, 0, stream>>>(token, Wq, Wkv, qk);
    ap_k1_sim<<<(BATCH * SEQ) / 8, 256, 0, stream>>>(x, qk, sim);
    ap_k2_softmax<<<BATCH * HEADS, 256, 0, stream>>>(sim);
    ap_k3_wsum<<<dim3(16, 16), 256, 0, stream>>>(x, sim, xpart);
    ap_k3b_combine<<<BATCH * HEADS, 256, 0, stream>>>(xpart, xbar);
    ap_k4_vproj<<<BATCH * HEADS, 256, 0, stream>>>(Wkv, xbar, om);
    ap_k5_final<<<dim3(16, 16), 256, 0, stream>>>(Wo, bo, om, out);
}

// Round 2
// 250.793 us; speedup vs baseline: 1.0728x; 1.0728x over previous
//
#include <hip/hip_runtime.h>

#define EMBED 1024
#define HEADS 8
#define DIM_HEAD 64
#define INNER 512
#define BATCH 16
#define SEQ 2048
// scale = DIM_HEAD^-0.5 = 0.125

// ws layout (floats):
//   q        @ 0        (512)
//   qk       @ 512      (8192)
//   partials @ 8704     (512 blocks * 8208)   per block: acc[8][1024], M[8]@8192, L[8]@8200
//   om       @ 4211200  (16*512)
#define WS_Q  0
#define WS_QK 512
#define WS_PART 8704
#define PART_STRIDE 8208
#define WS_OM 4211200

// ---------------------------------------------------------------------------
// F0a: q[i] = token . Wq[i]  (512 dots of len 1024). grid 64, block 256.
// Wave w computes outputs i0=blk*8+w*2, i0+1.
__global__ void ap_f0a_q(const float* __restrict__ token, const float* __restrict__ Wq,
                         float* __restrict__ q) {
    const int t = threadIdx.x;
    const int w = t >> 6, lane = t & 63;
    const int i0 = blockIdx.x * 8 + w * 2;
    const float4* tok4 = (const float4*)token;
    const float4* r0 = (const float4*)Wq + (long)i0 * 256;
    const float4* r1 = r0 + 256;
    float a0 = 0.f, a1 = 0.f;
#pragma unroll
    for (int k = 0; k < 4; ++k) {
        int e4 = k * 64 + lane;
        float4 tv = tok4[e4];
        float4 w0 = r0[e4];
        float4 w1 = r1[e4];
        a0 += tv.x * w0.x + tv.y * w0.y + tv.z * w0.z + tv.w * w0.w;
        a1 += tv.x * w1.x + tv.y * w1.y + tv.z * w1.z + tv.w * w1.w;
    }
#pragma unroll
    for (int off = 32; off; off >>= 1) {
        a0 += __shfl_xor(a0, off);
        a1 += __shfl_xor(a1, off);
    }
    if (lane == 0) { q[i0] = a0; q[i0 + 1] = a1; }
}

// ---------------------------------------------------------------------------
// F0b: qk[h][e] = 0.125 * sum_d q[h*64+d] * Wkv[h*64+d][e]
// grid 64 (h = blk>>3, echunk = blk&7), block 128.
__global__ void ap_f0b_qk(const float* __restrict__ q, const float* __restrict__ Wkv,
                          float* __restrict__ qk) {
    __shared__ float q_s[DIM_HEAD];
    const int h = blockIdx.x >> 3, ec = blockIdx.x & 7;
    const int t = threadIdx.x;
    if (t < 64) q_s[t] = q[h * 64 + t];
    __syncthreads();
    const int e = ec * 128 + t;
    float a = 0.f;
#pragma unroll 8
    for (int d = 0; d < 64; ++d)
        a += q_s[d] * Wkv[(long)(h * 64 + d) * EMBED + e];
    qk[h * EMBED + e] = 0.125f * a;
}

// ---------------------------------------------------------------------------
// F1: fused sim + online softmax + weighted x-sum. Single pass over x.
// grid 512 (b = blk>>5, slice = blk&31), block 256 = 4 waves.
// Wave handles 16 consecutive rows (2 per iteration, 8 iterations).
// Wave state: m[8], l[8], acc[8][4] float4 (lane's e-slice: e4 = k*64+lane).
// Block tail: combine 4 waves -> per-block partial (acc[8][1024], M[8], L[8]).
__global__ __launch_bounds__(256) void ap_f1_fused(const float* __restrict__ x,
                                                   const float* __restrict__ qk,
                                                   float* __restrict__ partials) {
    __shared__ float4 qk_s[HEADS * 256];   // 32 KB
    __shared__ float4 cmb[4][256];         // 16 KB
    __shared__ float ml_s[4][16];          // [wave][0..7]=m, [8..15]=l
    const int t = threadIdx.x;
    const int w = t >> 6, lane = t & 63;
    const int b = blockIdx.x >> 5, slice = blockIdx.x & 31;

    const float4* qk4 = (const float4*)qk;
#pragma unroll
    for (int j = 0; j < 8; ++j) qk_s[t + 256 * j] = qk4[t + 256 * j];
    __syncthreads();

    float m[8], l[8];
    float4 acc[8][4];
#pragma unroll
    for (int h = 0; h < 8; ++h) {
        m[h] = -3e38f; l[h] = 0.f;
#pragma unroll
        for (int k = 0; k < 4; ++k) acc[h][k] = make_float4(0.f, 0.f, 0.f, 0.f);
    }

    const long row0 = (long)b * SEQ + slice * 64 + w * 16;
    for (int iter = 0; iter < 8; ++iter) {
        const float4* xr0 = (const float4*)x + (row0 + iter * 2) * 256;
        const float4* xr1 = xr0 + 256;
        float4 x0[4], x1[4];
#pragma unroll
        for (int k = 0; k < 4; ++k) x0[k] = xr0[k * 64 + lane];
#pragma unroll
        for (int k = 0; k < 4; ++k) x1[k] = xr1[k * 64 + lane];

        float s0[8], s1[8];
#pragma unroll
        for (int h = 0; h < 8; ++h) { s0[h] = 0.f; s1[h] = 0.f; }
#pragma unroll
        for (int k = 0; k < 4; ++k) {
#pragma unroll
            for (int h = 0; h < 8; ++h) {
                float4 qv = qk_s[h * 256 + k * 64 + lane];
                s0[h] += qv.x * x0[k].x + qv.y * x0[k].y + qv.z * x0[k].z + qv.w * x0[k].w;
                s1[h] += qv.x * x1[k].x + qv.y * x1[k].y + qv.z * x1[k].z + qv.w * x1[k].w;
            }
        }
#pragma unroll
        for (int h = 0; h < 8; ++h) {
#pragma unroll
            for (int off = 32; off; off >>= 1) {
                s0[h] += __shfl_xor(s0[h], off);
                s1[h] += __shfl_xor(s1[h], off);
            }
        }
        // online softmax update (wave-uniform values)
#pragma unroll
        for (int h = 0; h < 8; ++h) {
            float mn = fmaxf(m[h], fmaxf(s0[h], s1[h]));
            if (mn > m[h]) {
                float corr = __expf(m[h] - mn);
                l[h] *= corr;
#pragma unroll
                for (int k = 0; k < 4; ++k) {
                    acc[h][k].x *= corr; acc[h][k].y *= corr;
                    acc[h][k].z *= corr; acc[h][k].w *= corr;
                }
                m[h] = mn;
            }
            float w0 = __expf(s0[h] - mn), w1 = __expf(s1[h] - mn);
            l[h] += w0 + w1;
#pragma unroll
            for (int k = 0; k < 4; ++k) {
                acc[h][k].x += w0 * x0[k].x + w1 * x1[k].x;
                acc[h][k].y += w0 * x0[k].y + w1 * x1[k].y;
                acc[h][k].z += w0 * x0[k].z + w1 * x1[k].z;
                acc[h][k].w += w0 * x0[k].w + w1 * x1[k].w;
            }
        }
    }

    // ---- block combine: 4 waves -> one partial ----
    if (lane == 0) {
#pragma unroll
        for (int h = 0; h < 8; ++h) { ml_s[w][h] = m[h]; ml_s[w][8 + h] = l[h]; }
    }
    __syncthreads();

    float fac[8];
#pragma unroll
    for (int h = 0; h < 8; ++h) {
        float Mh = fmaxf(fmaxf(ml_s[0][h], ml_s[1][h]), fmaxf(ml_s[2][h], ml_s[3][h]));
        fac[h] = __expf(m[h] - Mh);
    }

    float* pbase = partials + (long)blockIdx.x * PART_STRIDE;
    float4* pacc = (float4*)pbase;
    for (int h = 0; h < 8; ++h) {
#pragma unroll
        for (int k = 0; k < 4; ++k) {
            float4 v = acc[h][k];
            v.x *= fac[h]; v.y *= fac[h]; v.z *= fac[h]; v.w *= fac[h];
            cmb[w][k * 64 + lane] = v;
        }
        __syncthreads();
        float4 a = cmb[0][t], bb = cmb[1][t], c = cmb[2][t], d = cmb[3][t];
        float4 s;
        s.x = a.x + bb.x + c.x + d.x; s.y = a.y + bb.y + c.y + d.y;
        s.z = a.z + bb.z + c.z + d.z; s.w = a.w + bb.w + c.w + d.w;
        pacc[h * 256 + t] = s;
        __syncthreads();
    }
    if (t < 8) {
        float Mh = fmaxf(fmaxf(ml_s[0][t], ml_s[1][t]), fmaxf(ml_s[2][t], ml_s[3][t]));
        float L = 0.f;
#pragma unroll
        for (int ww = 0; ww < 4; ++ww)
            L += ml_s[ww][8 + t] * __expf(ml_s[ww][t] - Mh);
        pbase[8192 + t] = Mh;
        pbase[8200 + t] = L;
    }
}

// ---------------------------------------------------------------------------
// F2v: per (b,h): combine 32 block-partials -> xbar (LDS), then V-projection:
// om[b][h*64+d] = Wv_row(h,d) . xbar.  grid 128 (b = blk>>3, h = blk&7), block 256.
__global__ __launch_bounds__(256) void ap_f2v(const float* __restrict__ partials,
                                              const float* __restrict__ Wkv,
                                              float* __restrict__ om) {
    __shared__ float M_s[32], l_s[32];
    __shared__ float4 xb_s[256];
    const int b = blockIdx.x >> 3, h = blockIdx.x & 7;
    const int t = threadIdx.x;
    if (t < 32) {
        const float* pb = partials + (long)(b * 32 + t) * PART_STRIDE;
        M_s[t] = pb[8192 + h];
        l_s[t] = pb[8200 + h];
    }
    __syncthreads();
    float GM = -3e38f;
#pragma unroll
    for (int c = 0; c < 32; ++c) GM = fmaxf(GM, M_s[c]);
    float L = 0.f;
#pragma unroll
    for (int c = 0; c < 32; ++c) L += __expf(M_s[c] - GM) * l_s[c];

    float4 a = make_float4(0.f, 0.f, 0.f, 0.f);
    for (int c = 0; c < 32; ++c) {
        float sc = __expf(M_s[c] - GM);
        const float4* pa = (const float4*)(partials + (long)(b * 32 + c) * PART_STRIDE);
        float4 p = pa[h * 256 + t];
        a.x += sc * p.x; a.y += sc * p.y; a.z += sc * p.z; a.w += sc * p.w;
    }
    float inv = 1.f / L;
    a.x *= inv; a.y *= inv; a.z *= inv; a.w *= inv;
    xb_s[t] = a;
    __syncthreads();

    const int d = t >> 2, qq = t & 3;
    const float4* W4 = (const float4*)Wkv + (long)(INNER + h * DIM_HEAD + d) * 256;
    float accv = 0.f;
#pragma unroll 8
    for (int j = 0; j < 64; ++j) {
        int idx = qq + 4 * j;
        float4 wv = W4[idx];
        float4 xv = xb_s[idx];
        accv += wv.x * xv.x + wv.y * xv.y + wv.z * xv.z + wv.w * xv.w;
    }
    accv += __shfl_xor(accv, 1);
    accv += __shfl_xor(accv, 2);
    if (qq == 0) om[b * INNER + h * DIM_HEAD + d] = accv;
}

// ---------------------------------------------------------------------------
// k5: out[b][e] = bo[e] + om[b] . Wo[e]   grid (16 chunks of 64 e, 16 b), block 256
__global__ void ap_k5_final(const float* __restrict__ Wo, const float* __restrict__ bo,
                            const float* __restrict__ om, float* __restrict__ out) {
    __shared__ float4 om_s[INNER / 4];  // 2 KB
    const int chunk = blockIdx.x, b = blockIdx.y;
    const int t = threadIdx.x;
    if (t < 128) om_s[t] = ((const float4*)om)[b * (INNER / 4) + t];
    __syncthreads();
    const int eo = t >> 2, qq = t & 3;
    const int e = chunk * 64 + eo;
    const float4* W4 = (const float4*)Wo + (long)e * (INNER / 4);
    float acc = 0.f;
#pragma unroll 8
    for (int j = 0; j < 32; ++j) {
        int idx = qq + 4 * j;
        float4 w = W4[idx];
        float4 v = om_s[idx];
        acc += w.x * v.x + w.y * v.y + w.z * v.z + w.w * v.w;
    }
    acc += __shfl_xor(acc, 1);
    acc += __shfl_xor(acc, 2);
    if (qq == 0) out[b * EMBED + e] = acc + bo[e];
}

// ---------------------------------------------------------------------------
extern "C" void kernel_launch(void* const* d_in, const int* in_sizes, int n_in,
                              void* d_out, int out_size, void* d_ws, size_t ws_size,
                              hipStream_t stream) {
    const float* x     = (const float*)d_in[0];  // 16*2048*1024
    const float* token = (const float*)d_in[1];  // 1024
    const float* Wq    = (const float*)d_in[2];  // 512*1024
    const float* Wkv   = (const float*)d_in[3];  // 1024*1024
    const float* Wo    = (const float*)d_in[4];  // 1024*512
    const float* bo    = (const float*)d_in[5];  // 1024
    float* out = (float*)d_out;                  // 16*1024
    float* ws = (float*)d_ws;

    float* q        = ws + WS_Q;
    float* qk       = ws + WS_QK;
    float* partials = ws + WS_PART;
    float* om       = ws + WS_OM;

    ap_f0a_q<<<64, 256, 0, stream>>>(token, Wq, q);
    ap_f0b_qk<<<64, 128, 0, stream>>>(q, Wkv, qk);
    ap_f1_fused<<<512, 256, 0, stream>>>(x, qk, partials);
    ap_f2v<<<128, 256, 0, stream>>>(partials, Wkv, om);
    ap_k5_final<<<dim3(16, 16), 256, 0, stream>>>(Wo, bo, om, out);
}